// Round 2
// baseline (726.890 us; speedup 1.0000x reference)
//
#include <hip/hip_runtime.h>
#include <stdint.h>

#define NB   4096   // batch rows
#define LDIM 4096   // latent dim
#define KK   10     // k
#define TPB  256

__global__ __launch_bounds__(TPB) void topk_sparsemax(
    const float* __restrict__ logits,
    float* __restrict__ bv,      // [NB, KK, LDIM]
    float* __restrict__ distr,   // [NB, KK]
    float* __restrict__ ent)     // [1]
{
    __shared__ unsigned long long s_cand[4 * KK];  // 4 waves x top-10 candidates
    __shared__ float s_wsum[4];
    __shared__ int   s_pos[KK];
    __shared__ int   s_sign[KK];
    __shared__ int   s_bestm[KK];

    const int b    = blockIdx.x;
    const int t    = threadIdx.x;
    const int lane = t & 63;
    const int wv   = t >> 6;
    const float* __restrict__ row = logits + (size_t)b * LDIM;

    // ---- load 16 logits/thread, coalesced: element idx = (q<<10) + (t<<2) + j
    float vals[16];
#pragma unroll
    for (int q = 0; q < 4; q++) {
        const float4 f = *(const float4*)(row + (q << 10) + (t << 2));
        vals[q*4+0] = f.x; vals[q*4+1] = f.y; vals[q*4+2] = f.z; vals[q*4+3] = f.w;
    }

    // ---- bulk bv base write FIRST: stores stream on the vmem pipe while the
    //      selection below runs on VALU/LDS pipes. Fixup of <=100 flipped
    //      elements happens after the barriers (which drain these stores).
    float4 base4[4];
#pragma unroll
    for (int q = 0; q < 4; q++) {
        base4[q].x = vals[q*4+0] > 0.f ? 1.f : 0.f;
        base4[q].y = vals[q*4+1] > 0.f ? 1.f : 0.f;
        base4[q].z = vals[q*4+2] > 0.f ? 1.f : 0.f;
        base4[q].w = vals[q*4+3] > 0.f ? 1.f : 0.f;
    }
    float* out0 = bv + (size_t)b * (KK * LDIM);
#pragma unroll
    for (int c = 0; c < KK; c++) {
        float* orow = out0 + c * LDIM + (t << 2);
#pragma unroll
        for (int q = 0; q < 4; q++)
            *(float4*)(orow + (q << 10)) = base4[q];
    }

    // ---- S0 = sum of positive logits (wave reduce -> LDS; combined later)
    float s0 = 0.f;
#pragma unroll
    for (int i = 0; i < 16; i++) s0 += vals[i] > 0.f ? vals[i] : 0.f;
#pragma unroll
    for (int off = 1; off < 64; off <<= 1) s0 += __shfl_xor(s0, off, 64);
    if (lane == 0) s_wsum[wv] = s0;

    // ---- stage 1 (wave-local, ZERO barriers): each wave's 10 smallest |logit|
    // packed u64 = (cost_bits << 32) | (idx << 1) | sign; u64-min == stable top_k order
    unsigned int taken = 0u;
    for (int c = 0; c < KK; c++) {
        unsigned long long best = ~0ull;
#pragma unroll
        for (int i = 0; i < 16; i++) {
            if (!(taken & (1u << i))) {
                const float val  = vals[i];
                const float cost = fabsf(val);
                const int   idx  = ((i >> 2) << 10) + (t << 2) + (i & 3);
                const unsigned long long pk =
                    ((unsigned long long)__float_as_uint(cost) << 32)
                    | (unsigned)((idx << 1) | (val > 0.f ? 1 : 0));
                if (pk < best) best = pk;
            }
        }
#pragma unroll
        for (int off = 1; off < 64; off <<= 1) {
            const unsigned long long o = __shfl_xor(best, off, 64);
            if (o < best) best = o;
        }
        if (lane == 0) s_cand[wv * KK + c] = best;
        const unsigned lo = (unsigned)best;
        const int idx = (int)(lo >> 1);
        const int rem = idx & 1023;
        if ((rem >> 2) == t) taken |= 1u << (((idx >> 10) << 2) | (rem & 3));
    }
    __syncthreads();  // publishes candidates; also drains the bulk stores

    // ---- wave 0: merge 40 candidates -> global top-10, subset stage, sparsemax
    if (wv == 0) {
        unsigned long long cand = (lane < 4 * KK) ? s_cand[lane] : ~0ull;
        float csm[KK]; int pos[KK]; int sgn[KK];
#pragma unroll
        for (int c = 0; c < KK; c++) {
            unsigned long long w = cand;
#pragma unroll
            for (int off = 1; off < 64; off <<= 1) {
                const unsigned long long o = __shfl_xor(w, off, 64);
                if (o < w) w = o;
            }
            if (cand == w) cand = ~0ull;  // retire winner (all packed values distinct)
            const unsigned lo = (unsigned)w;
            pos[c] = (int)(lo >> 1);
            sgn[c] = (int)(lo & 1u);
            csm[c] = __uint_as_float((unsigned)(w >> 32));
        }

        // 1024 subset sums, 16/lane; ascending-bit accumulation == einsum rounding
        float sums[16];
#pragma unroll
        for (int i = 0; i < 16; i++) {
            const int m = (lane << 4) | i;
            float acc = 0.f;
#pragma unroll
            for (int j = 0; j < KK; j++) acc += (m & (1 << j)) ? csm[j] : 0.f;
            sums[i] = acc;
        }
        unsigned int taken2 = 0u;
        int bm[KK]; float cst[KK];
        for (int c = 0; c < KK; c++) {
            unsigned long long best = ~0ull;
#pragma unroll
            for (int i = 0; i < 16; i++) {
                if (!(taken2 & (1u << i))) {
                    const unsigned long long pk =
                        ((unsigned long long)__float_as_uint(sums[i]) << 32)
                        | (unsigned)((lane << 4) | i);
                    if (pk < best) best = pk;
                }
            }
#pragma unroll
            for (int off = 1; off < 64; off <<= 1) {
                const unsigned long long o = __shfl_xor(best, off, 64);
                if (o < best) best = o;
            }
            const int m = (int)(unsigned)best;
            if ((m >> 4) == lane) taken2 |= 1u << (m & 15);
            bm[c]  = m;
            cst[c] = __uint_as_float((unsigned)(best >> 32));
        }

        if (lane == 0) {
#pragma unroll
            for (int c = 0; c < KK; c++) {
                s_pos[c] = pos[c]; s_sign[c] = sgn[c]; s_bestm[c] = bm[c];
            }
            const float S0 = (s_wsum[0] + s_wsum[1]) + (s_wsum[2] + s_wsum[3]);
            float z[KK];
#pragma unroll
            for (int c = 0; c < KK; c++) z[c] = S0 - cst[c];
            float acc = 0.f; int ks = 0;
#pragma unroll
            for (int r = 1; r <= KK; r++) {
                acc += z[r-1];
                if (1.f + (float)r * z[r-1] > acc) ks++;
            }
            float acc2 = 0.f;
#pragma unroll
            for (int r = 0; r < KK; r++) if (r < ks) acc2 += z[r];
            const float tau = (acc2 - 1.f) / (float)ks;
            float entl = 0.f;
            float* drow = distr + b * KK;
#pragma unroll
            for (int c = 0; c < KK; c++) {
                float p = z[c] - tau;
                p = p > 0.f ? p : 0.f;
                drow[c] = p;
                if (p > 0.f) entl -= p * logf(p);
            }
            atomicAdd(ent, entl * (1.0f / (float)NB));
        }
    }
    __syncthreads();

    // ---- flip fixup: bulk stores drained at barrier 1, so these overwrite safely
    if (t < KK * KK) {
        const int c = t / KK, j = t % KK;
        if ((s_bestm[c] >> j) & 1)
            out0[c * LDIM + s_pos[j]] = s_sign[j] ? 0.f : 1.f;
    }
}

extern "C" void kernel_launch(void* const* d_in, const int* in_sizes, int n_in,
                              void* d_out, int out_size, void* d_ws, size_t ws_size,
                              hipStream_t stream)
{
    const float* logits = (const float*)d_in[0];
    float* out   = (float*)d_out;
    float* bv    = out;
    float* distr = out + (size_t)NB * KK * LDIM;
    float* ent   = distr + (size_t)NB * KK;
    // harness poisons d_out with 0xAA before timed replays; entropy is accumulated
    hipMemsetAsync(ent, 0, sizeof(float), stream);
    topk_sparsemax<<<dim3(NB), dim3(TPB), 0, stream>>>(logits, bv, distr, ent);
}